// Round 6
// baseline (167.293 us; speedup 1.0000x reference)
//
#include <hip/hip_runtime.h>
#include <hip/hip_bf16.h>

typedef __bf16 bf16;
typedef __bf16 bf16x4 __attribute__((ext_vector_type(4)));
typedef __bf16 bf16x8 __attribute__((ext_vector_type(8)));
typedef float f32x4 __attribute__((ext_vector_type(4)));

#define MFMA16(a, b, c) __builtin_amdgcn_mfma_f32_16x16x32_bf16((a), (b), (c), 0, 0, 0)

// async global->LDS, 16B per lane; LDS dest = wave-uniform base + lane*16.
__device__ __forceinline__ void async16(const void* g, void* l) {
  typedef const unsigned int __attribute__((address_space(1))) * GP;
  typedef unsigned int __attribute__((address_space(3))) * LP;
  __builtin_amdgcn_global_load_lds((GP)g, (LP)l, 16, 0, 0);
}

// ---------------------------------------------------------------------------
// prep: z<4 -> transpose+convert weight z (fp32 [1024x1024] -> bf16 Wt[n][k]);
// z==4 -> convert x fp32 -> bf16. grid (16,16,5) x 256 threads.
// ---------------------------------------------------------------------------
__global__ __launch_bounds__(256) void prep(
    const float* __restrict__ w0, const float* __restrict__ w1,
    const float* __restrict__ w2, const float* __restrict__ w3,
    const float* __restrict__ x, bf16* __restrict__ wtOut,
    bf16* __restrict__ xOut) {
  const int t = threadIdx.x;
  if (blockIdx.z == 4) {  // x conversion
    size_t base = ((size_t)(blockIdx.y * 16 + blockIdx.x)) * 16384;
#pragma unroll
    for (int p = 0; p < 16; ++p) {
      size_t i = base + (size_t)(p * 256 + t) * 4;
      f32x4 v = *(const f32x4*)&x[i];
      bf16 o[4];
#pragma unroll
      for (int j = 0; j < 4; ++j) o[j] = (bf16)v[j];
      *(ulong1*)&xOut[i] = *(ulong1*)o;
    }
    return;
  }
  __shared__ __align__(16) float tile[64][68];
  const float* src = (blockIdx.z == 0) ? w0 : (blockIdx.z == 1) ? w1
                   : (blockIdx.z == 2) ? w2 : w3;
  bf16* dst = wtOut + (size_t)blockIdx.z * (1024u * 1024u);
  const int bx = blockIdx.x, by = blockIdx.y;
#pragma unroll
  for (int p = 0; p < 4; ++p) {
    int idx = t + p * 256;
    int r = idx >> 4, c4 = idx & 15;
    *(f32x4*)&tile[r][c4 * 4] =
        *(const f32x4*)&src[(size_t)(by * 64 + r) * 1024 + bx * 64 + c4 * 4];
  }
  __syncthreads();
#pragma unroll
  for (int p = 0; p < 2; ++p) {
    int idx = t + p * 256;
    int rn = idx >> 3, c8 = idx & 7;
    bf16x8 v;
#pragma unroll
    for (int i = 0; i < 8; ++i) v[i] = (bf16)tile[c8 * 8 + i][rn];
    *(bf16x8*)&dst[(size_t)(bx * 64 + rn) * 1024 + by * 64 + c8 * 8] = v;
  }
}

// ---------------------------------------------------------------------------
// GEMM (round-13 config). C = A @ W (Bt[n][k]). 128 x (NI*32) tile, BK=32
// dbuf global_load_lds, one barrier per K-step. XCD-swizzled 1D grid.
// z==0 scaled by scaleZ0; z==2 with vtOut: fused V^T epilogue with the
// PI-PERMUTED key layout. QKV: NI=4 (grid 256/z). proj: NI=2 (grid 512).
// ---------------------------------------------------------------------------
template <typename OutT, int NI>
__global__ __launch_bounds__(256, 4) void gemm_bt(
    const bf16* __restrict__ A, const bf16* __restrict__ Bt,
    OutT* __restrict__ C, int btStrideZ, int cStrideZ, float scaleZ0,
    bf16* __restrict__ vtOut) {
  constexpr int XT = 1024 / (NI * 32);
  const int bid = blockIdx.x;
  const int rr = bid & 7, tt = bid >> 3;
  const int xb = tt % XT, yb = (tt / XT) * 8 + rr;
  const int zi = blockIdx.y;

  const int tid = threadIdx.x;
  const int wave = tid >> 6, lane = tid & 63;
  const int quad = lane >> 4, l16 = lane & 15;
  const int wm = wave >> 1, wn = wave & 1;
  const int m0 = yb * 128, n0 = xb * (NI * 32);
  const bf16* Bz = Bt + (size_t)zi * (size_t)btStrideZ;
  OutT* Cz = C + (size_t)zi * (size_t)cStrideZ;
  const float sc = (zi == 0) ? scaleZ0 : 1.0f;

  __shared__ __align__(16) bf16 lsA[2][128 * 32];
  __shared__ __align__(16) bf16 lsB[2][NI * 32 * 32];

  const int lrow = lane >> 2;
  const int cgX = (lane & 3) ^ ((lrow >> 1) & 3);
  const int fR = (l16 >> 1) & 3;

  f32x4 acc[4][NI];
#pragma unroll
  for (int i = 0; i < 4; ++i)
#pragma unroll
    for (int j = 0; j < NI; ++j) acc[i][j] = (f32x4){0.f, 0.f, 0.f, 0.f};

#pragma unroll
  for (int c = 0; c < 2; ++c) {
    int chunk = wave * 2 + c;
    int row = chunk * 16 + lrow;
    async16(&A[(size_t)(m0 + row) * 1024 + cgX * 8], &lsA[0][chunk * 512]);
  }
#pragma unroll
  for (int c = 0; c < NI / 2; ++c) {
    int chunk = wave * (NI / 2) + c;
    int row = chunk * 16 + lrow;
    async16(&Bz[(size_t)(n0 + row) * 1024 + cgX * 8], &lsB[0][chunk * 512]);
  }
  __syncthreads();

  for (int it = 0; it < 32; ++it) {
    const int cur = it & 1;
    if (it < 31) {
      int k0n = (it + 1) * 32;
#pragma unroll
      for (int c = 0; c < 2; ++c) {
        int chunk = wave * 2 + c;
        int row = chunk * 16 + lrow;
        async16(&A[(size_t)(m0 + row) * 1024 + k0n + cgX * 8],
                &lsA[cur ^ 1][chunk * 512]);
      }
#pragma unroll
      for (int c = 0; c < NI / 2; ++c) {
        int chunk = wave * (NI / 2) + c;
        int row = chunk * 16 + lrow;
        async16(&Bz[(size_t)(n0 + row) * 1024 + k0n + cgX * 8],
                &lsB[cur ^ 1][chunk * 512]);
      }
    }

    bf16x8 af[4], bfr[NI];
#pragma unroll
    for (int i = 0; i < 4; ++i) {
      int ra = wm * 64 + i * 16 + l16;
      af[i] = *(const bf16x8*)&lsA[cur][ra * 32 + ((quad ^ fR) * 8)];
    }
#pragma unroll
    for (int ni = 0; ni < NI; ++ni) {
      int rb = wn * (NI * 16) + ni * 16 + l16;
      bfr[ni] = *(const bf16x8*)&lsB[cur][rb * 32 + ((quad ^ fR) * 8)];
    }
#pragma unroll
    for (int mi = 0; mi < 4; ++mi)
#pragma unroll
      for (int ni = 0; ni < NI; ++ni)
        acc[mi][ni] = MFMA16(af[mi], bfr[ni], acc[mi][ni]);

    __syncthreads();
  }

  if (zi == 2 && vtOut != nullptr) {
    // V: transposed per head -> vt[(b*16+h)][d][sPerm], pi-permuted keys.
#pragma unroll
    for (int mi = 0; mi < 4; ++mi)
#pragma unroll
      for (int ni = 0; ni < NI; ++ni) {
        int col = n0 + wn * (NI * 16) + ni * 16 + l16;
        int hd = col >> 6, d = col & 63;
        int row = m0 + wm * 64 + mi * 16 + quad * 4;
        int b = row >> 11, s = row & 2047;
        int s32 = s & 31;
        int sp = (s & ~31) + ((s32 & 12) << 1) + ((s32 >> 4) << 2);
        bf16 o[4];
#pragma unroll
        for (int r = 0; r < 4; ++r) o[r] = (bf16)acc[mi][ni][r];
        *(ulong1*)&vtOut[((size_t)(b * 16 + hd) * 64 + d) * 2048 + sp] =
            *(ulong1*)o;
      }
  } else {
#pragma unroll
    for (int mi = 0; mi < 4; ++mi)
#pragma unroll
      for (int ni = 0; ni < NI; ++ni) {
        int col = n0 + wn * (NI * 16) + ni * 16 + l16;
#pragma unroll
        for (int r = 0; r < 4; ++r) {
          int row = m0 + wm * 64 + mi * 16 + quad * 4 + r;
          Cz[(size_t)row * 1024 + col] = (OutT)(acc[mi][ni][r] * sc);
        }
      }
  }
}

// ---------------------------------------------------------------------------
// Flash attention v11 (R6): LDS-read amortization ON TOP of the R5 occupancy
// fix. R5 confirmed occupancy was the binding constraint (+9us); with 16
// waves/CU resident the next floor is LDS read redundancy: v10's 4 waves
// each read the FULL K/V tile (16 b128/tile) for only 16 q-rows -> ~21us of
// LDS-pipe time vs ~7us MFMA. v11: each wave owns 32 q-rows (v8.1's verified
// 2-q-group inner body: one K/V frag feeds 2 B-frags), block = 128 rows,
// 4 waves, grid 512. LDS = 2 K/V slots (32KB) + Q 16KB = 48KB -> 3 blk/CU,
// all 512 blocks resident (768 slots). Reads per q-row HALVED (~11us floor).
// Why not the v8 failures again: R1 failed on VGPR (128-cap; now cap 170 at
// 3 w/SIMD, live ~110), R2 was masked by the occupancy bind (now removed).
// No parity split -> no combine epilogue. Diagonal: ktd = 2qt + (wave>>1)
// (waves 0,1 = rows 0..63 stop at tile 2qt; waves 2,3 at 2qt+1).
// qt pairing j<8?j:23-j keeps per-CU work balanced under bid%256 placement.
// ---------------------------------------------------------------------------
__global__ __launch_bounds__(256, 3) void attn_fwd(
    const bf16* __restrict__ Q, const bf16* __restrict__ K,
    const bf16* __restrict__ Vt, bf16* __restrict__ O) {
  const int bid = blockIdx.x;
  const int xcd = bid & 7;       // hardware: bid%8 -> XCD
  const int i = bid >> 3;        // 0..63 within XCD
  const int g4 = i & 3;          // (b,h) group within XCD (4 groups = 2MB L2)
  const int j = i >> 2;          // 0..15 q-tile slot
  const int qt = (j < 8) ? j : (23 - j);  // pairs (j, j+8) sum to 15
  const int bh = xcd * 4 + g4;
  const int h = bh & 15, b = bh >> 4;
  const int tid = threadIdx.x;
  const int wave = tid >> 6, lane = tid & 63;
  const int quad = lane >> 4, l16 = lane & 15;

  __shared__ __align__(16) bf16 SMEM[24576];  // 48KB: 2x(K8K+V8K) + Q 16K
  bf16* Qs = &SMEM[16384];

  const size_t base = ((size_t)b * 2048) * 1024 + (size_t)h * 64;
  const bf16* Qb = Q + base;
  const bf16* Kb = K + base;
  const bf16* Vtb = Vt + ((size_t)(b * 16 + h)) * 64 * 2048;
  bf16* Ob = O + base;

  const int lrow = lane >> 3;
  const int cgX = (lane & 7) ^ lrow;

  // prologue: stage Q (16KB, 16 chunks) + K/V tile 0 (16KB)
#pragma unroll
  for (int c = 0; c < 4; ++c) {
    int chunk = wave * 4 + c;
    int row = chunk * 8 + lrow;
    async16(&Qb[(size_t)(qt * 128 + row) * 1024 + cgX * 8], &Qs[chunk * 512]);
  }
#pragma unroll
  for (int c = 0; c < 2; ++c) {
    int chunk = wave * 2 + c;
    int row = chunk * 8 + lrow;
    async16(&Kb[(size_t)row * 1024 + cgX * 8], &SMEM[chunk * 512]);
    async16(&Vtb[(size_t)row * 2048 + cgX * 8], &SMEM[4096 + chunk * 512]);
  }
  __syncthreads();

  bf16x8 aq[2][2];  // [q-subgroup g][k-chunk]
#pragma unroll
  for (int g = 0; g < 2; ++g)
#pragma unroll
    for (int ks = 0; ks < 2; ++ks) {
      int row = wave * 32 + g * 16 + l16;
      aq[g][ks] =
          *(const bf16x8*)&Qs[row * 64 + (((ks * 4 + quad) ^ (l16 & 7)) * 8)];
    }

  const float NEG_INF = -__builtin_inff();
  f32x4 lsv[2];
  f32x4 Oacc[2][4];
#pragma unroll
  for (int g = 0; g < 2; ++g) {
    lsv[g] = (f32x4){0.f, 0.f, 0.f, 0.f};
#pragma unroll
    for (int nt = 0; nt < 4; ++nt) Oacc[g][nt] = (f32x4){0.f, 0.f, 0.f, 0.f};
  }

  const int ktmax = 2 * qt + 1;            // 64-key tiles: 2qt+2 total
  const int ktd = 2 * qt + (wave >> 1);    // this wave's diagonal tile

  for (int kt = 0; kt <= ktmax; ++kt) {
    const int cur = kt & 1;
    if (kt < ktmax) {  // prefetch tile kt+1 into the other slot
      const int ns = (cur ^ 1) * 8192;
#pragma unroll
      for (int c = 0; c < 2; ++c) {
        int chunk = wave * 2 + c;
        int row = chunk * 8 + lrow;
        async16(&Kb[(size_t)((kt + 1) * 64 + row) * 1024 + cgX * 8],
                &SMEM[ns + chunk * 512]);
        async16(&Vtb[(size_t)row * 2048 + (kt + 1) * 64 + cgX * 8],
                &SMEM[ns + 4096 + chunk * 512]);
      }
    }

    const int ko = cur * 8192;
    const int vo = ko + 4096;

    if (kt <= ktd) {
      const int cb = (kt - 2 * qt) * 64;  // key offset within 128-row block
      const bool diag = (kt == ktd);
#pragma unroll
      for (int a = 0; a < 2; ++a) {  // key-half: keys [a*32, a*32+32)
        f32x4 s[2][2];               // [g][t]
#pragma unroll
        for (int t = 0; t < 2; ++t) {
          const int nt = 2 * a + t;
          const int row = nt * 16 + l16;
          bf16x8 bk0 =
              *(const bf16x8*)&SMEM[ko + row * 64 + ((quad ^ (l16 & 7)) * 8)];
          bf16x8 bk1 = *(const bf16x8*)&SMEM[ko + row * 64 +
                                             (((4 + quad) ^ (l16 & 7)) * 8)];
          __builtin_amdgcn_s_setprio(1);
#pragma unroll
          for (int g = 0; g < 2; ++g) {
            f32x4 sv = (f32x4){0.f, 0.f, 0.f, 0.f};
            sv = MFMA16(bk0, aq[g][0], sv);
            sv = MFMA16(bk1, aq[g][1], sv);
            s[g][t] = sv;
          }
          __builtin_amdgcn_s_setprio(0);
        }

        if (diag) {
#pragma unroll
          for (int g = 0; g < 2; ++g) {
            const int q_rel = wave * 32 + g * 16 + l16;
#pragma unroll
            for (int t = 0; t < 2; ++t) {
              const int kb = cb + (2 * a + t) * 16 + quad * 4;
#pragma unroll
              for (int r = 0; r < 4; ++r)
                if (kb + r > q_rel) s[g][t][r] = NEG_INF;
            }
          }
        }

        bf16x8 apf[2];  // per-g P fragment for this key-half
#pragma unroll
        for (int g = 0; g < 2; ++g) {
#pragma unroll
          for (int t = 0; t < 2; ++t) {
#pragma unroll
            for (int r = 0; r < 4; ++r)
              s[g][t][r] = __builtin_amdgcn_exp2f(s[g][t][r]);
            lsv[g] += s[g][t];
          }
          bf16x4 c0 = __builtin_convertvector(s[g][0], bf16x4);
          bf16x4 c1 = __builtin_convertvector(s[g][1], bf16x4);
#pragma unroll
          for (int i2 = 0; i2 < 4; ++i2) {
            apf[g][i2] = c0[i2];
            apf[g][4 + i2] = c1[i2];
          }
        }

        // PV for this key-half: one V-frag serves both q-subgroups.
#pragma unroll
        for (int nt = 0; nt < 4; ++nt) {
          const int R = nt * 16 + l16;
          bf16x8 bvf = *(const bf16x8*)&SMEM[vo + R * 64 +
                                             (((a * 4 + quad) ^ (l16 & 7)) *
                                              8)];
          __builtin_amdgcn_s_setprio(1);
#pragma unroll
          for (int g = 0; g < 2; ++g)
            Oacc[g][nt] = MFMA16(apf[g], bvf, Oacc[g][nt]);
          __builtin_amdgcn_s_setprio(0);
        }
      }
    }

    __syncthreads();  // tile kt reads done + tile kt+1 landed (vmcnt drain)
  }

  // Per-g softmax denominator: sum r, then across quads (q = l16 per wave-g).
  float ls[2];
#pragma unroll
  for (int g = 0; g < 2; ++g) {
    float a_ = lsv[g][0] + lsv[g][1] + lsv[g][2] + lsv[g][3];
    a_ += __shfl_xor(a_, 16, 64);
    a_ += __shfl_xor(a_, 32, 64);
    ls[g] = a_;
  }
  float rl[2][4];
#pragma unroll
  for (int g = 0; g < 2; ++g)
#pragma unroll
    for (int r = 0; r < 4; ++r)
      rl[g][r] = 1.f / __shfl(ls[g], quad * 4 + r, 64);
#pragma unroll
  for (int g = 0; g < 2; ++g)
#pragma unroll
    for (int nt = 0; nt < 4; ++nt)
#pragma unroll
      for (int r = 0; r < 4; ++r) {
        int row = qt * 128 + wave * 32 + g * 16 + quad * 4 + r;
        Ob[(size_t)row * 1024 + nt * 16 + l16] =
            (bf16)(Oacc[g][nt][r] * rl[g][r]);
      }
}

// ---------------------------------------------------------------------------
// Launch
// ---------------------------------------------------------------------------
extern "C" void kernel_launch(void* const* d_in, const int* in_sizes, int n_in,
                              void* d_out, int out_size, void* d_ws,
                              size_t ws_size, hipStream_t stream) {
  (void)in_sizes; (void)n_in; (void)out_size; (void)ws_size;
  const float* x  = (const float*)d_in[0];
  const float* Wq = (const float*)d_in[1];
  const float* Wk = (const float*)d_in[2];
  const float* Wv = (const float*)d_in[3];
  const float* Wo = (const float*)d_in[4];
  float* out = (float*)d_out;

  bf16* ws = (bf16*)d_ws;
  const size_t WELEM = 1024u * 1024u;
  const size_t TELEM = 4096u * 1024u;
  bf16* wt  = ws;               // 4 transposed weights (8 MB)
  bf16* xbf = ws + 4 * WELEM;   // x bf16 (8 MB)
  bf16* q   = xbf + TELEM;      // q (z=0), k (z=1) via cStrideZ
  bf16* k   = q + TELEM;
  bf16* vt  = k + TELEM;        // V pre-transposed + pi-permuted by QKV
  bf16* ao  = vt + TELEM;

  const float QSCALE = 0.125f * 1.44269504088896340736f;  // 1/sqrt(64)*log2e

  prep<<<dim3(16, 16, 5), 256, 0, stream>>>(Wq, Wk, Wv, Wo, x, wt, xbf);
  gemm_bt<bf16, 4><<<dim3(256, 3), 256, 0, stream>>>(
      xbf, wt, q, (int)WELEM, (int)TELEM, QSCALE, vt);
  attn_fwd<<<dim3(512), 256, 0, stream>>>(q, k, vt, ao);
  gemm_bt<float, 2><<<dim3(512, 1), 256, 0, stream>>>(
      ao, wt + 3 * WELEM, out, 0, 0, 1.0f, nullptr);
}

// Round 7
// 158.539 us; speedup vs baseline: 1.0552x; 1.0552x over previous
//
#include <hip/hip_runtime.h>
#include <hip/hip_bf16.h>

typedef __bf16 bf16;
typedef __bf16 bf16x4 __attribute__((ext_vector_type(4)));
typedef __bf16 bf16x8 __attribute__((ext_vector_type(8)));
typedef float f32x4 __attribute__((ext_vector_type(4)));

#define MFMA16(a, b, c) __builtin_amdgcn_mfma_f32_16x16x32_bf16((a), (b), (c), 0, 0, 0)

// async global->LDS, 16B per lane; LDS dest = wave-uniform base + lane*16.
__device__ __forceinline__ void async16(const void* g, void* l) {
  typedef const unsigned int __attribute__((address_space(1))) * GP;
  typedef unsigned int __attribute__((address_space(3))) * LP;
  __builtin_amdgcn_global_load_lds((GP)g, (LP)l, 16, 0, 0);
}

// ---------------------------------------------------------------------------
// prep: z<4 -> transpose+convert weight z (fp32 [1024x1024] -> bf16 Wt[n][k]);
// z==4 -> convert x fp32 -> bf16. grid (16,16,5) x 256 threads.
// ---------------------------------------------------------------------------
__global__ __launch_bounds__(256) void prep(
    const float* __restrict__ w0, const float* __restrict__ w1,
    const float* __restrict__ w2, const float* __restrict__ w3,
    const float* __restrict__ x, bf16* __restrict__ wtOut,
    bf16* __restrict__ xOut) {
  const int t = threadIdx.x;
  if (blockIdx.z == 4) {  // x conversion
    size_t base = ((size_t)(blockIdx.y * 16 + blockIdx.x)) * 16384;
#pragma unroll
    for (int p = 0; p < 16; ++p) {
      size_t i = base + (size_t)(p * 256 + t) * 4;
      f32x4 v = *(const f32x4*)&x[i];
      bf16 o[4];
#pragma unroll
      for (int j = 0; j < 4; ++j) o[j] = (bf16)v[j];
      *(ulong1*)&xOut[i] = *(ulong1*)o;
    }
    return;
  }
  __shared__ __align__(16) float tile[64][68];
  const float* src = (blockIdx.z == 0) ? w0 : (blockIdx.z == 1) ? w1
                   : (blockIdx.z == 2) ? w2 : w3;
  bf16* dst = wtOut + (size_t)blockIdx.z * (1024u * 1024u);
  const int bx = blockIdx.x, by = blockIdx.y;
#pragma unroll
  for (int p = 0; p < 4; ++p) {
    int idx = t + p * 256;
    int r = idx >> 4, c4 = idx & 15;
    *(f32x4*)&tile[r][c4 * 4] =
        *(const f32x4*)&src[(size_t)(by * 64 + r) * 1024 + bx * 64 + c4 * 4];
  }
  __syncthreads();
#pragma unroll
  for (int p = 0; p < 2; ++p) {
    int idx = t + p * 256;
    int rn = idx >> 3, c8 = idx & 7;
    bf16x8 v;
#pragma unroll
    for (int i = 0; i < 8; ++i) v[i] = (bf16)tile[c8 * 8 + i][rn];
    *(bf16x8*)&dst[(size_t)(bx * 64 + rn) * 1024 + by * 64 + c8 * 8] = v;
  }
}

// ---------------------------------------------------------------------------
// GEMM (round-13 config). C = A @ W (Bt[n][k]). 128 x (NI*32) tile, BK=32
// dbuf global_load_lds, one barrier per K-step. XCD-swizzled 1D grid.
// z==0 scaled by scaleZ0; z==2 with vtOut: fused V^T epilogue with the
// PI-PERMUTED key layout. QKV: NI=4 (grid 256/z). proj: NI=2 (grid 512).
// ---------------------------------------------------------------------------
template <typename OutT, int NI>
__global__ __launch_bounds__(256, 4) void gemm_bt(
    const bf16* __restrict__ A, const bf16* __restrict__ Bt,
    OutT* __restrict__ C, int btStrideZ, int cStrideZ, float scaleZ0,
    bf16* __restrict__ vtOut) {
  constexpr int XT = 1024 / (NI * 32);
  const int bid = blockIdx.x;
  const int rr = bid & 7, tt = bid >> 3;
  const int xb = tt % XT, yb = (tt / XT) * 8 + rr;
  const int zi = blockIdx.y;

  const int tid = threadIdx.x;
  const int wave = tid >> 6, lane = tid & 63;
  const int quad = lane >> 4, l16 = lane & 15;
  const int wm = wave >> 1, wn = wave & 1;
  const int m0 = yb * 128, n0 = xb * (NI * 32);
  const bf16* Bz = Bt + (size_t)zi * (size_t)btStrideZ;
  OutT* Cz = C + (size_t)zi * (size_t)cStrideZ;
  const float sc = (zi == 0) ? scaleZ0 : 1.0f;

  __shared__ __align__(16) bf16 lsA[2][128 * 32];
  __shared__ __align__(16) bf16 lsB[2][NI * 32 * 32];

  const int lrow = lane >> 2;
  const int cgX = (lane & 3) ^ ((lrow >> 1) & 3);
  const int fR = (l16 >> 1) & 3;

  f32x4 acc[4][NI];
#pragma unroll
  for (int i = 0; i < 4; ++i)
#pragma unroll
    for (int j = 0; j < NI; ++j) acc[i][j] = (f32x4){0.f, 0.f, 0.f, 0.f};

#pragma unroll
  for (int c = 0; c < 2; ++c) {
    int chunk = wave * 2 + c;
    int row = chunk * 16 + lrow;
    async16(&A[(size_t)(m0 + row) * 1024 + cgX * 8], &lsA[0][chunk * 512]);
  }
#pragma unroll
  for (int c = 0; c < NI / 2; ++c) {
    int chunk = wave * (NI / 2) + c;
    int row = chunk * 16 + lrow;
    async16(&Bz[(size_t)(n0 + row) * 1024 + cgX * 8], &lsB[0][chunk * 512]);
  }
  __syncthreads();

  for (int it = 0; it < 32; ++it) {
    const int cur = it & 1;
    if (it < 31) {
      int k0n = (it + 1) * 32;
#pragma unroll
      for (int c = 0; c < 2; ++c) {
        int chunk = wave * 2 + c;
        int row = chunk * 16 + lrow;
        async16(&A[(size_t)(m0 + row) * 1024 + k0n + cgX * 8],
                &lsA[cur ^ 1][chunk * 512]);
      }
#pragma unroll
      for (int c = 0; c < NI / 2; ++c) {
        int chunk = wave * (NI / 2) + c;
        int row = chunk * 16 + lrow;
        async16(&Bz[(size_t)(n0 + row) * 1024 + k0n + cgX * 8],
                &lsB[cur ^ 1][chunk * 512]);
      }
    }

    bf16x8 af[4], bfr[NI];
#pragma unroll
    for (int i = 0; i < 4; ++i) {
      int ra = wm * 64 + i * 16 + l16;
      af[i] = *(const bf16x8*)&lsA[cur][ra * 32 + ((quad ^ fR) * 8)];
    }
#pragma unroll
    for (int ni = 0; ni < NI; ++ni) {
      int rb = wn * (NI * 16) + ni * 16 + l16;
      bfr[ni] = *(const bf16x8*)&lsB[cur][rb * 32 + ((quad ^ fR) * 8)];
    }
#pragma unroll
    for (int mi = 0; mi < 4; ++mi)
#pragma unroll
      for (int ni = 0; ni < NI; ++ni)
        acc[mi][ni] = MFMA16(af[mi], bfr[ni], acc[mi][ni]);

    __syncthreads();
  }

  if (zi == 2 && vtOut != nullptr) {
    // V: transposed per head -> vt[(b*16+h)][d][sPerm], pi-permuted keys.
#pragma unroll
    for (int mi = 0; mi < 4; ++mi)
#pragma unroll
      for (int ni = 0; ni < NI; ++ni) {
        int col = n0 + wn * (NI * 16) + ni * 16 + l16;
        int hd = col >> 6, d = col & 63;
        int row = m0 + wm * 64 + mi * 16 + quad * 4;
        int b = row >> 11, s = row & 2047;
        int s32 = s & 31;
        int sp = (s & ~31) + ((s32 & 12) << 1) + ((s32 >> 4) << 2);
        bf16 o[4];
#pragma unroll
        for (int r = 0; r < 4; ++r) o[r] = (bf16)acc[mi][ni][r];
        *(ulong1*)&vtOut[((size_t)(b * 16 + hd) * 64 + d) * 2048 + sp] =
            *(ulong1*)o;
      }
  } else {
#pragma unroll
    for (int mi = 0; mi < 4; ++mi)
#pragma unroll
      for (int ni = 0; ni < NI; ++ni) {
        int col = n0 + wn * (NI * 16) + ni * 16 + l16;
#pragma unroll
        for (int r = 0; r < 4; ++r) {
          int row = m0 + wm * 64 + mi * 16 + quad * 4 + r;
          Cz[(size_t)row * 1024 + col] = (OutT)(acc[mi][ni][r] * sc);
        }
      }
  }
}

// ---------------------------------------------------------------------------
// Flash attention v12 (R7): v10's EXACT shell (grid 1024, 256 thr, 40KB LDS,
// 4 blk/CU, 16 waves/CU, 2-slot rotation, 1 barrier/tile — R6 proved the
// 4-independent-blocks/CU structure dominates; v8/v11 lost it and lost) with
// the wave->work map changed to halve LDS reads: wave = (qh=wave>>1,
// kh=wave&1) computes q-rows [qh*32,+32) x keys [kh*32,+32) of each tile.
// K/V reads per wave per tile: 8 b128 (half tile) serving 2 q-subgroups ->
// block-tile reads 64 -> 32 b128. MFMA/exp2 totals unchanged. Cost: cross-kh
// O/l combine via 20KB LDS scratch (reuses K/V slots after final barrier)
// + 1 barrier. Diagonal tile kt==qt: wave (qh0,kh1) fully masked -> skips;
// others mask key_rel > q_rel. Register liveness ~110 < the 128 cap of
// (256,4) (v8.1's verified budget).
// ---------------------------------------------------------------------------
__global__ __launch_bounds__(256, 4) void attn_fwd(
    const bf16* __restrict__ Q, const bf16* __restrict__ K,
    const bf16* __restrict__ Vt, bf16* __restrict__ O) {
  const int bid = blockIdx.x;
  const int xcd = bid & 7;       // hardware: bid%8 -> XCD
  const int i = bid >> 3;        // 0..127 within XCD
  const int g4 = i & 3;          // (b,h) group within XCD
  const int j = i >> 2;          // 0..31 q-tile slot
  const int a = j & 7, bq = j >> 3;
  // big-first, pair-balanced: {31-2a, 30-2a, 2a, 2a+1} per strided CU group
  const int qt = (bq < 2) ? (31 - 2 * a - bq) : (2 * a + (bq & 1));
  const int bh = xcd * 4 + g4;
  const int h = bh & 15, b = bh >> 4;
  const int tid = threadIdx.x;
  const int wave = tid >> 6, lane = tid & 63;
  const int quad = lane >> 4, l16 = lane & 15;
  const int qh = wave >> 1;  // q-half: rows [qh*32, qh*32+32)
  const int kh = wave & 1;   // key-half: keys [kh*32, kh*32+32) per tile

  __shared__ __align__(16) bf16 SMEM[20480];  // 40KB: 2x(K8K+V8K) + Q 8K
  bf16* Qs = &SMEM[16384];

  const size_t base = ((size_t)b * 2048) * 1024 + (size_t)h * 64;
  const bf16* Qb = Q + base;
  const bf16* Kb = K + base;
  const bf16* Vtb = Vt + ((size_t)(b * 16 + h)) * 64 * 2048;
  bf16* Ob = O + base;

  const int lrow = lane >> 3;
  const int cgX = (lane & 7) ^ lrow;

  // prologue: stage Q (8KB) + tile 0 (16KB)
#pragma unroll
  for (int c = 0; c < 2; ++c) {
    int chunk = wave * 2 + c;
    int row = chunk * 8 + lrow;
    async16(&Qb[(size_t)(qt * 64 + row) * 1024 + cgX * 8], &Qs[chunk * 512]);
    async16(&Kb[(size_t)row * 1024 + cgX * 8], &SMEM[chunk * 512]);
    async16(&Vtb[(size_t)row * 2048 + cgX * 8], &SMEM[4096 + chunk * 512]);
  }
  __syncthreads();

  bf16x8 aq[2][2];  // [q-subgroup g][d-chunk]
#pragma unroll
  for (int g = 0; g < 2; ++g)
#pragma unroll
    for (int ks = 0; ks < 2; ++ks) {
      int row = qh * 32 + g * 16 + l16;
      aq[g][ks] =
          *(const bf16x8*)&Qs[row * 64 + (((ks * 4 + quad) ^ (l16 & 7)) * 8)];
    }

  const float NEG_INF = -__builtin_inff();
  f32x4 lsv[2];
  f32x4 Oacc[2][4];
#pragma unroll
  for (int g = 0; g < 2; ++g) {
    lsv[g] = (f32x4){0.f, 0.f, 0.f, 0.f};
#pragma unroll
    for (int nt = 0; nt < 4; ++nt) Oacc[g][nt] = (f32x4){0.f, 0.f, 0.f, 0.f};
  }

  for (int kt = 0; kt <= qt; ++kt) {
    const int cur = kt & 1;
    if (kt < qt) {  // prefetch tile kt+1 into the other slot
      const int ns = (cur ^ 1) * 8192;
#pragma unroll
      for (int c = 0; c < 2; ++c) {
        int chunk = wave * 2 + c;
        int row = chunk * 8 + lrow;
        async16(&Kb[(size_t)((kt + 1) * 64 + row) * 1024 + cgX * 8],
                &SMEM[ns + chunk * 512]);
        async16(&Vtb[(size_t)row * 2048 + (kt + 1) * 64 + cgX * 8],
                &SMEM[ns + 4096 + chunk * 512]);
      }
    }

    const int ko = cur * 8192;
    const int vo = ko + 4096;
    const bool diag = (kt == qt);

    // wave (qh=0,kh=1) at diag: all keys > all q-rows -> fully masked, skip.
    if (!(diag && kh == 1 && qh == 0)) {
      f32x4 s[2][2];  // [g][t], t = 16-key block within this wave's half
#pragma unroll
      for (int t = 0; t < 2; ++t) {
        const int row = kh * 32 + t * 16 + l16;
        bf16x8 bk0 =
            *(const bf16x8*)&SMEM[ko + row * 64 + ((quad ^ (l16 & 7)) * 8)];
        bf16x8 bk1 = *(const bf16x8*)&SMEM[ko + row * 64 +
                                           (((4 + quad) ^ (l16 & 7)) * 8)];
        __builtin_amdgcn_s_setprio(1);
#pragma unroll
        for (int g = 0; g < 2; ++g) {
          f32x4 sv = (f32x4){0.f, 0.f, 0.f, 0.f};
          sv = MFMA16(bk0, aq[g][0], sv);
          sv = MFMA16(bk1, aq[g][1], sv);
          s[g][t] = sv;
        }
        __builtin_amdgcn_s_setprio(0);
      }

      if (diag) {
#pragma unroll
        for (int g = 0; g < 2; ++g) {
          const int q_rel = qh * 32 + g * 16 + l16;
#pragma unroll
          for (int t = 0; t < 2; ++t) {
            const int kb = kh * 32 + t * 16 + quad * 4;
#pragma unroll
            for (int r = 0; r < 4; ++r)
              if (kb + r > q_rel) s[g][t][r] = NEG_INF;
          }
        }
      }

      bf16x8 apf[2];  // per-g P fragment for this wave's 32-key half
#pragma unroll
      for (int g = 0; g < 2; ++g) {
#pragma unroll
        for (int t = 0; t < 2; ++t) {
#pragma unroll
          for (int r = 0; r < 4; ++r)
            s[g][t][r] = __builtin_amdgcn_exp2f(s[g][t][r]);
          lsv[g] += s[g][t];
        }
        bf16x4 c0 = __builtin_convertvector(s[g][0], bf16x4);
        bf16x4 c1 = __builtin_convertvector(s[g][1], bf16x4);
#pragma unroll
        for (int i2 = 0; i2 < 4; ++i2) {
          apf[g][i2] = c0[i2];
          apf[g][4 + i2] = c1[i2];
        }
      }

      // PV: V^T rows d = nt*16+l16, key-cols = this wave's half (kh).
#pragma unroll
      for (int nt = 0; nt < 4; ++nt) {
        const int R = nt * 16 + l16;
        bf16x8 bvf = *(const bf16x8*)&SMEM[vo + R * 64 +
                                           (((kh * 4 + quad) ^ (l16 & 7)) *
                                            8)];
        __builtin_amdgcn_s_setprio(1);
#pragma unroll
        for (int g = 0; g < 2; ++g)
          Oacc[g][nt] = MFMA16(apf[g], bvf, Oacc[g][nt]);
        __builtin_amdgcn_s_setprio(0);
      }
    }

    __syncthreads();  // tile kt reads done + tile kt+1 landed (vmcnt drain)
  }

  // Cross-kh combine: kh=1 -> LDS scratch (reuses K/V slots, all reads done),
  // kh=0 adds, reduces denominator, normalizes, stores.
  float* F = (float*)SMEM;
  const int qoff = qh * 2560;  // 2048 O floats + 512 lsv floats per q-half
  if (kh == 1) {
#pragma unroll
    for (int g = 0; g < 2; ++g) {
#pragma unroll
      for (int nt = 0; nt < 4; ++nt)
        *(f32x4*)&F[qoff + (g * 4 + nt) * 256 + lane * 4] = Oacc[g][nt];
      *(f32x4*)&F[qoff + 2048 + g * 256 + lane * 4] = lsv[g];
    }
  }
  __syncthreads();
  if (kh == 0) {
#pragma unroll
    for (int g = 0; g < 2; ++g) {
#pragma unroll
      for (int nt = 0; nt < 4; ++nt)
        Oacc[g][nt] += *(const f32x4*)&F[qoff + (g * 4 + nt) * 256 + lane * 4];
      lsv[g] += *(const f32x4*)&F[qoff + 2048 + g * 256 + lane * 4];
    }
    float ls[2];
#pragma unroll
    for (int g = 0; g < 2; ++g) {
      float a_ = lsv[g][0] + lsv[g][1] + lsv[g][2] + lsv[g][3];
      a_ += __shfl_xor(a_, 16, 64);
      a_ += __shfl_xor(a_, 32, 64);
      ls[g] = a_;
    }
    float rl[2][4];
#pragma unroll
    for (int g = 0; g < 2; ++g)
#pragma unroll
      for (int r = 0; r < 4; ++r)
        rl[g][r] = 1.f / __shfl(ls[g], quad * 4 + r, 64);
#pragma unroll
    for (int g = 0; g < 2; ++g)
#pragma unroll
      for (int nt = 0; nt < 4; ++nt)
#pragma unroll
        for (int r = 0; r < 4; ++r) {
          int row = qt * 64 + qh * 32 + g * 16 + quad * 4 + r;
          Ob[(size_t)row * 1024 + nt * 16 + l16] =
              (bf16)(Oacc[g][nt][r] * rl[g][r]);
        }
  }
}

// ---------------------------------------------------------------------------
// Launch
// ---------------------------------------------------------------------------
extern "C" void kernel_launch(void* const* d_in, const int* in_sizes, int n_in,
                              void* d_out, int out_size, void* d_ws,
                              size_t ws_size, hipStream_t stream) {
  (void)in_sizes; (void)n_in; (void)out_size; (void)ws_size;
  const float* x  = (const float*)d_in[0];
  const float* Wq = (const float*)d_in[1];
  const float* Wk = (const float*)d_in[2];
  const float* Wv = (const float*)d_in[3];
  const float* Wo = (const float*)d_in[4];
  float* out = (float*)d_out;

  bf16* ws = (bf16*)d_ws;
  const size_t WELEM = 1024u * 1024u;
  const size_t TELEM = 4096u * 1024u;
  bf16* wt  = ws;               // 4 transposed weights (8 MB)
  bf16* xbf = ws + 4 * WELEM;   // x bf16 (8 MB)
  bf16* q   = xbf + TELEM;      // q (z=0), k (z=1) via cStrideZ
  bf16* k   = q + TELEM;
  bf16* vt  = k + TELEM;        // V pre-transposed + pi-permuted by QKV
  bf16* ao  = vt + TELEM;

  const float QSCALE = 0.125f * 1.44269504088896340736f;  // 1/sqrt(64)*log2e

  prep<<<dim3(16, 16, 5), 256, 0, stream>>>(Wq, Wk, Wv, Wo, x, wt, xbf);
  gemm_bt<bf16, 4><<<dim3(256, 3), 256, 0, stream>>>(
      xbf, wt, q, (int)WELEM, (int)TELEM, QSCALE, vt);
  attn_fwd<<<dim3(1024), 256, 0, stream>>>(q, k, vt, ao);
  gemm_bt<float, 2><<<dim3(512, 1), 256, 0, stream>>>(
      ao, wt + 3 * WELEM, out, 0, 0, 1.0f, nullptr);
}